// Round 8
// baseline (631.099 us; speedup 1.0000x reference)
//
#include <hip/hip_runtime.h>
#include <hip/hip_fp16.h>
#include <math.h>

#define NN 50000
#define EE 800000
#define DD 512
#define HH 256
#define KK 16
#define NB_SCAN 196  // ceil(NN/256)

typedef _Float16 half8_t __attribute__((ext_vector_type(8)));
typedef float f32x4 __attribute__((ext_vector_type(4)));

// ---------------- fused degree count (blocks 0..781) + weight transpose (782..1549) ----------
// Safe to fuse again (cf. r4 regression): scatter now lives inside gemm1, so only the
// ~1MB scan kernels run between this and gemm1 — Wt1/Wt2 (384 KB) stay hot in L2.
__global__ void count_transpose(const int4* __restrict__ src4, const int4* __restrict__ dst4,
                                int* __restrict__ indeg, int* __restrict__ outdeg,
                                const float* __restrict__ W1, __half* __restrict__ Wt1,
                                const float* __restrict__ W2, __half* __restrict__ Wt2) {
    int bx = blockIdx.x;
    if (bx < 782) {
        int e = bx * 256 + threadIdx.x;
        if (e < EE / 4) {
            int4 s = src4[e], d = dst4[e];
            atomicAdd(&outdeg[s.x], 1); atomicAdd(&outdeg[s.y], 1);
            atomicAdd(&outdeg[s.z], 1); atomicAdd(&outdeg[s.w], 1);
            atomicAdd(&indeg[d.x], 1);  atomicAdd(&indeg[d.y], 1);
            atomicAdd(&indeg[d.z], 1);  atomicAdd(&indeg[d.w], 1);
        }
    } else {
        int i = (bx - 782) * 256 + threadIdx.x;
        if (i < DD * HH) {
            int k = i / HH, n = i % HH;
            Wt1[(size_t)n * DD + k] = __float2half(W1[i]);
        } else if (i < DD * HH + HH * HH) {
            int j = i - DD * HH;
            int k = j / HH, n = j % HH;
            Wt2[(size_t)n * HH + k] = __float2half(W2[j]);
        }
    }
}

// ---------------- 3-phase multi-block exclusive scan (+node_prep fused in p1) ----------------
__global__ void scan_p1(const int* __restrict__ in, int* __restrict__ part, int n,
                        const int* __restrict__ outdeg, float* __restrict__ dis,
                        float* __restrict__ degf) {
    __shared__ int tile[256];
    int t = threadIdx.x;
    int i = blockIdx.x * 256 + t;
    int v = (i < n) ? in[i] : 0;
    tile[t] = v;
    if (i < n) {
        dis[i]  = 1.0f / sqrtf(1.0f + (float)v);
        degf[i] = (float)outdeg[i];
    }
    __syncthreads();
    for (int o = 128; o > 0; o >>= 1) {
        if (t < o) tile[t] += tile[t + o];
        __syncthreads();
    }
    if (t == 0) part[blockIdx.x] = tile[0];
}

__global__ void scan_p2(int* __restrict__ part, int nb, int* __restrict__ off_end) {
    __shared__ int tile[256];
    int t = threadIdx.x;
    int v = (t < nb) ? part[t] : 0;
    tile[t] = v;
    __syncthreads();
    for (int o = 1; o < 256; o <<= 1) {
        int x = (t >= o) ? tile[t - o] : 0;
        __syncthreads();
        tile[t] += x;
        __syncthreads();
    }
    if (t < nb) part[t] = tile[t] - v;  // exclusive base per block
    if (t == 255) *off_end = tile[255];
}

__global__ void scan_p3(const int* __restrict__ in, const int* __restrict__ part,
                        int* __restrict__ out, int n) {
    __shared__ int tile[256];
    int t = threadIdx.x;
    int i = blockIdx.x * 256 + t;
    int v = (i < n) ? in[i] : 0;
    tile[t] = v;
    __syncthreads();
    for (int o = 1; o < 256; o <<= 1) {
        int x = (t >= o) ? tile[t - o] : 0;
        __syncthreads();
        tile[t] += x;
        __syncthreads();
    }
    if (i < n) out[i] = part[blockIdx.x] + tile[t] - v;
}

// ---------------- fused gemm1 (blocks 0..783) + CSR scatter (blocks 784..1565) ----------------
__global__ __launch_bounds__(256) void gemm1_scatter(
        const float* __restrict__ A, const __half* __restrict__ Bt,
        __half* __restrict__ C, int M,
        const int4* __restrict__ src4, const int4* __restrict__ dst4,
        const int* __restrict__ off, int* __restrict__ cur, int* __restrict__ nbr) {
    constexpr int SROW = 36;
    constexpr int EPG  = 4;
    constexpr int GPR  = 8;
    constexpr int RPP  = 32;
    constexpr int NP   = 4;
    constexpr int KI   = DD / 32;

    __shared__ float As[2][128 * SROW];

    int b = blockIdx.x;
    int t = threadIdx.x;
    if (b >= 784) {
        int e = (b - 784) * 256 + t;
        if (e < EE / 4) {
            int4 s = src4[e], d = dst4[e];
            int p;
            p = atomicAdd(&cur[d.x], 1); nbr[off[d.x] + p] = s.x;
            p = atomicAdd(&cur[d.y], 1); nbr[off[d.y] + p] = s.y;
            p = atomicAdd(&cur[d.z], 1); nbr[off[d.z] + p] = s.z;
            p = atomicAdd(&cur[d.w], 1); nbr[off[d.w] + p] = s.w;
        }
        return;
    }

    int wave = t >> 6, lane = t & 63, quad = lane >> 4, l16 = lane & 15;
    int row0 = (b >> 1) * 128, col0 = (b & 1) * 128;
    int wm = (wave & 1) * 64, wn = (wave >> 1) * 64;
    int srow = t / GPR, sg = t % GPR;

    f32x4 acc[4][4] = {};
    uint4 sreg[NP];
    uint4 bcur[4];

    const __half* brow[4];
#pragma unroll
    for (int ni = 0; ni < 4; ni++)
        brow[ni] = Bt + (size_t)(col0 + wn + ni * 16 + l16) * DD + quad * 8;

    auto gloadA = [&](int k0) {
#pragma unroll
        for (int p = 0; p < NP; p++) {
            int gr = row0 + p * RPP + srow;
            if (gr < M)
                sreg[p] = *(const uint4*)(A + (size_t)gr * DD + k0 + sg * EPG);
            else
                sreg[p] = make_uint4(0, 0, 0, 0);
        }
    };
    auto sstore = [&](int buf) {
#pragma unroll
        for (int p = 0; p < NP; p++)
            *(uint4*)&As[buf][(p * RPP + srow) * SROW + sg * EPG] = sreg[p];
    };

    gloadA(0);
#pragma unroll
    for (int ni = 0; ni < 4; ni++) bcur[ni] = *(const uint4*)(brow[ni]);
    sstore(0);
    __syncthreads();

#pragma unroll
    for (int i = 0; i < KI; i++) {
        int cur_b = i & 1;
        uint4 bnext[4];
        if (i + 1 < KI) {
            gloadA((i + 1) * 32);
#pragma unroll
            for (int ni = 0; ni < 4; ni++)
                bnext[ni] = *(const uint4*)(brow[ni] + (i + 1) * 32);
        }

        half8_t af[4];
#pragma unroll
        for (int mi = 0; mi < 4; mi++) {
            int row = wm + mi * 16 + l16;
            const float* pl = &As[cur_b][0] + row * SROW + quad * 8;
            float4 x0 = *(const float4*)pl;
            float4 x1 = *(const float4*)(pl + 4);
            half8_t h;
            h[0] = (_Float16)x0.x; h[1] = (_Float16)x0.y;
            h[2] = (_Float16)x0.z; h[3] = (_Float16)x0.w;
            h[4] = (_Float16)x1.x; h[5] = (_Float16)x1.y;
            h[6] = (_Float16)x1.z; h[7] = (_Float16)x1.w;
            af[mi] = h;
        }
#pragma unroll
        for (int mi = 0; mi < 4; mi++)
#pragma unroll
            for (int ni = 0; ni < 4; ni++)
                acc[mi][ni] = __builtin_amdgcn_mfma_f32_16x16x32_f16(
                    af[mi], *(half8_t*)&bcur[ni], acc[mi][ni], 0, 0, 0);

        if (i + 1 < KI) {
            sstore(cur_b ^ 1);
#pragma unroll
            for (int ni = 0; ni < 4; ni++) bcur[ni] = bnext[ni];
        }
        __syncthreads();
    }

#pragma unroll
    for (int mi = 0; mi < 4; mi++) {
#pragma unroll
        for (int r = 0; r < 4; r++) {
            int rr = row0 + wm + mi * 16 + quad * 4 + r;
            if (rr < M) {
#pragma unroll
                for (int ni = 0; ni < 4; ni++) {
                    C[(size_t)rr * HH + col0 + wn + ni * 16 + l16] =
                        __float2half(acc[mi][ni][r]);
                }
            }
        }
    }
}

// ---------------- MFMA f16 GEMM (gemm2): C[M,256] = A[M,KDIM] @ Wt[256,KDIM]^T ----------------
template <typename TA, int KDIM>
__global__ __launch_bounds__(256) void mfma_gemm(const TA* __restrict__ A,
                                                 const __half* __restrict__ Bt,
                                                 __half* __restrict__ C, int M) {
    constexpr bool F32 = sizeof(TA) == 4;
    constexpr int SROW = F32 ? 36 : 40;
    constexpr int EPG  = F32 ? 4 : 8;
    constexpr int GPR  = 32 / EPG;
    constexpr int RPP  = 256 / GPR;
    constexpr int NP   = 128 / RPP;
    constexpr int KI   = KDIM / 32;

    __shared__ TA As[2][128 * SROW];

    int t = threadIdx.x;
    int wave = t >> 6, lane = t & 63, quad = lane >> 4, l16 = lane & 15;
    int row0 = blockIdx.x * 128, col0 = blockIdx.y * 128;
    int wm = (wave & 1) * 64, wn = (wave >> 1) * 64;
    int srow = t / GPR, sg = t % GPR;

    f32x4 acc[4][4] = {};
    uint4 sreg[NP];
    uint4 bcur[4];

    const __half* brow[4];
#pragma unroll
    for (int ni = 0; ni < 4; ni++)
        brow[ni] = Bt + (size_t)(col0 + wn + ni * 16 + l16) * KDIM + quad * 8;

    auto gloadA = [&](int k0) {
#pragma unroll
        for (int p = 0; p < NP; p++) {
            int gr = row0 + p * RPP + srow;
            if (gr < M)
                sreg[p] = *(const uint4*)(A + (size_t)gr * KDIM + k0 + sg * EPG);
            else
                sreg[p] = make_uint4(0, 0, 0, 0);
        }
    };
    auto sstore = [&](int buf) {
#pragma unroll
        for (int p = 0; p < NP; p++)
            *(uint4*)&As[buf][(p * RPP + srow) * SROW + sg * EPG] = sreg[p];
    };

    gloadA(0);
#pragma unroll
    for (int ni = 0; ni < 4; ni++) bcur[ni] = *(const uint4*)(brow[ni]);
    sstore(0);
    __syncthreads();

#pragma unroll
    for (int i = 0; i < KI; i++) {
        int cur = i & 1;
        uint4 bnext[4];
        if (i + 1 < KI) {
            gloadA((i + 1) * 32);
#pragma unroll
            for (int ni = 0; ni < 4; ni++)
                bnext[ni] = *(const uint4*)(brow[ni] + (i + 1) * 32);
        }

        half8_t af[4];
#pragma unroll
        for (int mi = 0; mi < 4; mi++) {
            int row = wm + mi * 16 + l16;
            if constexpr (F32) {
                const float* pl = (const float*)&As[cur][0] + row * SROW + quad * 8;
                float4 x0 = *(const float4*)pl;
                float4 x1 = *(const float4*)(pl + 4);
                half8_t h;
                h[0] = (_Float16)x0.x; h[1] = (_Float16)x0.y;
                h[2] = (_Float16)x0.z; h[3] = (_Float16)x0.w;
                h[4] = (_Float16)x1.x; h[5] = (_Float16)x1.y;
                h[6] = (_Float16)x1.z; h[7] = (_Float16)x1.w;
                af[mi] = h;
            } else {
                af[mi] = *(const half8_t*)&As[cur][row * SROW + quad * 8];
            }
        }
#pragma unroll
        for (int mi = 0; mi < 4; mi++)
#pragma unroll
            for (int ni = 0; ni < 4; ni++)
                acc[mi][ni] = __builtin_amdgcn_mfma_f32_16x16x32_f16(
                    af[mi], *(half8_t*)&bcur[ni], acc[mi][ni], 0, 0, 0);

        if (i + 1 < KI) {
            sstore(cur ^ 1);
#pragma unroll
            for (int ni = 0; ni < 4; ni++) bcur[ni] = bnext[ni];
        }
        __syncthreads();
    }

#pragma unroll
    for (int mi = 0; mi < 4; mi++) {
#pragma unroll
        for (int r = 0; r < 4; r++) {
            int rr = row0 + wm + mi * 16 + quad * 4 + r;
            if (rr < M) {
#pragma unroll
                for (int ni = 0; ni < 4; ni++) {
                    C[(size_t)rr * HH + col0 + wn + ni * 16 + l16] =
                        __float2half(acc[mi][ni][r]);
                }
            }
        }
    }
}

// ---------------- aggregation + bias + SELU (conv1: plain, writes f16) ----------------
__device__ inline void fma8(float* acc, uint4 raw, float w) {
    const __half2* h = (const __half2*)&raw;
#pragma unroll
    for (int i = 0; i < 4; i++) {
        float2 f = __half22float2(h[i]);
        acc[2 * i]     += w * f.x;
        acc[2 * i + 1] += w * f.y;
    }
}

__device__ inline void agg_body(const __half* __restrict__ T, const float* __restrict__ dis,
                                const int* __restrict__ off, const int* __restrict__ nbr,
                                int n, int c, float dn, float* acc) {
#pragma unroll
    for (int i = 0; i < 8; i++) acc[i] = 0.f;
    fma8(acc, *(const uint4*)(T + (size_t)n * HH + c), dn * dn);  // self-loop

    int s0 = off[n], s1 = off[n + 1];
    int l32 = c >> 3;
    for (int base = s0; base < s1; base += 32) {
        int cnt = min(32, s1 - base);
        int sidv = 0; float sdsv = 0.f;
        if (l32 < cnt) {
            sidv = nbr[base + l32];
            sdsv = dis[sidv] * dn;
        }
        int j = 0;
        for (; j + 8 <= cnt; j += 8) {
            int a0 = __shfl(sidv, j, 32),     a1 = __shfl(sidv, j + 1, 32);
            int a2 = __shfl(sidv, j + 2, 32), a3 = __shfl(sidv, j + 3, 32);
            int a4 = __shfl(sidv, j + 4, 32), a5 = __shfl(sidv, j + 5, 32);
            int a6 = __shfl(sidv, j + 6, 32), a7 = __shfl(sidv, j + 7, 32);
            float w0 = __shfl(sdsv, j, 32),     w1 = __shfl(sdsv, j + 1, 32);
            float w2 = __shfl(sdsv, j + 2, 32), w3 = __shfl(sdsv, j + 3, 32);
            float w4 = __shfl(sdsv, j + 4, 32), w5 = __shfl(sdsv, j + 5, 32);
            float w6 = __shfl(sdsv, j + 6, 32), w7 = __shfl(sdsv, j + 7, 32);
            uint4 r0 = *(const uint4*)(T + (size_t)a0 * HH + c);
            uint4 r1 = *(const uint4*)(T + (size_t)a1 * HH + c);
            uint4 r2 = *(const uint4*)(T + (size_t)a2 * HH + c);
            uint4 r3 = *(const uint4*)(T + (size_t)a3 * HH + c);
            uint4 r4 = *(const uint4*)(T + (size_t)a4 * HH + c);
            uint4 r5 = *(const uint4*)(T + (size_t)a5 * HH + c);
            uint4 r6 = *(const uint4*)(T + (size_t)a6 * HH + c);
            uint4 r7 = *(const uint4*)(T + (size_t)a7 * HH + c);
            fma8(acc, r0, w0); fma8(acc, r1, w1);
            fma8(acc, r2, w2); fma8(acc, r3, w3);
            fma8(acc, r4, w4); fma8(acc, r5, w5);
            fma8(acc, r6, w6); fma8(acc, r7, w7);
        }
        for (; j < cnt; j++) {
            int s = __shfl(sidv, j, 32);
            float w = __shfl(sdsv, j, 32);
            fma8(acc, *(const uint4*)(T + (size_t)s * HH + c), w);
        }
    }
}

__global__ __launch_bounds__(256) void agg_selu(const __half* __restrict__ T,
                                                const float* __restrict__ dis,
                                                const int* __restrict__ off,
                                                const int* __restrict__ nbr,
                                                const float* __restrict__ bias,
                                                __half* out) {
    int t = threadIdx.x;
    int l32 = t & 31;
    int n = blockIdx.x * 8 + (t >> 5);
    int c = l32 * 8;
    float dn = dis[n];

    float acc[8];
    agg_body(T, dis, off, nbr, n, c, dn, acc);

    const float scale = 1.0507009873554805f;
    const float alpha = 1.6732632423543772f;
    float4 b0 = *(const float4*)(bias + c);
    float4 b1 = *(const float4*)(bias + c + 4);
    float bb[8] = {b0.x, b0.y, b0.z, b0.w, b1.x, b1.y, b1.z, b1.w};
    _Float16 res[8];
#pragma unroll
    for (int i = 0; i < 8; i++) {
        float v = acc[i] + bb[i];
        float r = v > 0.f ? scale * v : scale * alpha * expm1f(v);
        res[i] = (_Float16)r;
    }
    *(uint4*)(out + (size_t)n * HH + c) = *(uint4*)res;
}

// ---------------- conv2 aggregation + SELU + skip + FUSED assignment head ----------------
// Each 32-lane group owns one node's full 256-wide row (8 ch/lane, f32 in regs).
// Head: stage Wa permuted in LDS as wa_l[i][k][lane] (bank==lane: conflict-free;
// upper half-wave reads identical addrs = free broadcast), 128 LDS-FMA/lane,
// 5-step shfl_xor(..,32) reduce, lane-local softmax. Eliminates Hb write (25.6MB),
// the assign dispatch, and its 25.6MB re-read. No f16 Ah (trace reads f32 out).
__global__ __launch_bounds__(256) void agg_selu_assign(
        const __half* __restrict__ T, const float* __restrict__ dis,
        const int* __restrict__ off, const int* __restrict__ nbr,
        const float* __restrict__ bias, const __half* __restrict__ skip,
        const float* __restrict__ Wa, const float* __restrict__ ba,
        const float* __restrict__ degf,
        float* __restrict__ out_assign, float* __restrict__ scal) {
    __shared__ float wa_l[8 * 16 * 32];  // 16 KB, [i][k][g]
    __shared__ float sba[16];
    __shared__ float sacc[33];

    int t = threadIdx.x;
    int l32 = t & 31;
    int n = blockIdx.x * 8 + (t >> 5);
    int c = l32 * 8;

    // stage Wa[(g*8+i)*16+k] -> wa_l[(i*16+k)*32+g]
    for (int idx = t; idx < 4096; idx += 256) {
        int row = idx >> 4, k = idx & 15;
        wa_l[((row & 7) * 16 + k) * 32 + (row >> 3)] = Wa[idx];
    }
    if (t < 16) sba[t] = ba[t];
    if (t < 33) sacc[t] = 0.f;
    __syncthreads();

    float dn = dis[n];
    float acc[8];
    agg_body(T, dis, off, nbr, n, c, dn, acc);

    const float scale = 1.0507009873554805f;
    const float alpha = 1.6732632423543772f;
    float4 b0 = *(const float4*)(bias + c);
    float4 b1 = *(const float4*)(bias + c + 4);
    float bb[8] = {b0.x, b0.y, b0.z, b0.w, b1.x, b1.y, b1.z, b1.w};
    uint4 skraw = *(const uint4*)(skip + (size_t)n * HH + c);
    const __half2* skh = (const __half2*)&skraw;

    float hv[8];
#pragma unroll
    for (int i = 0; i < 8; i++) {
        float v = acc[i] + bb[i];
        float r = v > 0.f ? scale * v : scale * alpha * expm1f(v);
        float2 f = __half22float2(skh[i >> 1]);
        hv[i] = r + ((i & 1) ? f.y : f.x);
    }

    // logits: p[k] = sum_i hv[i] * Wa[c+i][k]
    float p[16];
#pragma unroll
    for (int k = 0; k < 16; k++) p[k] = 0.f;
#pragma unroll
    for (int i = 0; i < 8; i++)
#pragma unroll
        for (int k = 0; k < 16; k++)
            p[k] += hv[i] * wa_l[(i * 16 + k) * 32 + l32];
#pragma unroll
    for (int o = 1; o < 32; o <<= 1)
#pragma unroll
        for (int k = 0; k < 16; k++)
            p[k] += __shfl_xor(p[k], o, 32);
#pragma unroll
    for (int k = 0; k < 16; k++) p[k] += sba[k];

    // softmax over 16 (every lane holds full logits; redundant but cheap)
    float mx = p[0];
#pragma unroll
    for (int k = 1; k < 16; k++) mx = fmaxf(mx, p[k]);
    float s = 0.f;
#pragma unroll
    for (int k = 0; k < 16; k++) { p[k] = expf(p[k] - mx); s += p[k]; }
    float inv = 1.f / s;
    float ent = 0.f;
#pragma unroll
    for (int k = 0; k < 16; k++) { p[k] *= inv; ent += p[k] * logf(p[k] + 1e-8f); }

    float dgf = degf[n];
    if (l32 == 0) {
        float4* ov = (float4*)(out_assign + (size_t)n * KK);
        ov[0] = make_float4(p[0], p[1], p[2], p[3]);
        ov[1] = make_float4(p[4], p[5], p[6], p[7]);
        ov[2] = make_float4(p[8], p[9], p[10], p[11]);
        ov[3] = make_float4(p[12], p[13], p[14], p[15]);
#pragma unroll
        for (int k = 0; k < 16; k++) {
            atomicAdd(&sacc[k], p[k]);
            atomicAdd(&sacc[16 + k], dgf * p[k]);
        }
        atomicAdd(&sacc[32], ent);
    }
    __syncthreads();
    if (t < 32) atomicAdd(&scal[t], sacc[t]);
    else if (t == 32) atomicAdd(&scal[33], sacc[32]);
}

// ---------------- fused tail: edge_trace (blocks 0..781, f32 assignments) + pooled ----------
__device__ inline float dot16f(const float* a, const float* b) {
    float p = 0.f;
#pragma unroll
    for (int q = 0; q < 4; q++) {
        float4 u = ((const float4*)a)[q], v = ((const float4*)b)[q];
        p += u.x * v.x + u.y * v.y + u.z * v.z + u.w * v.w;
    }
    return p;
}

#define PCH 125
__global__ __launch_bounds__(256) void trace_pooled(const int4* __restrict__ src4,
                                                    const int4* __restrict__ dst4,
                                                    float* __restrict__ scal,
                                                    const float* __restrict__ emb,
                                                    const float* __restrict__ assign,
                                                    float* __restrict__ part) {
    __shared__ float sa[PCH * KK];  // 8 KB; sa[0] doubles as the trace scratch
    int bx = blockIdx.x, t = threadIdx.x;
    if (bx < 782) {
        int e = bx * 256 + t;
        float p = 0.f;
        if (e < EE / 4) {
            int4 s = src4[e], d = dst4[e];
            p += dot16f(assign + (size_t)s.x * KK, assign + (size_t)d.x * KK);
            p += dot16f(assign + (size_t)s.y * KK, assign + (size_t)d.y * KK);
            p += dot16f(assign + (size_t)s.z * KK, assign + (size_t)d.z * KK);
            p += dot16f(assign + (size_t)s.w * KK, assign + (size_t)d.w * KK);
        }
        for (int o = 32; o >= 1; o >>= 1) p += __shfl_xor(p, o);
        if (t == 0) sa[0] = 0.f;
        __syncthreads();
        if ((t & 63) == 0) atomicAdd(&sa[0], p);
        __syncthreads();
        if (t == 0) atomicAdd(&scal[32], sa[0]);
    } else {
        int j = bx - 782;
        int d = (j & 1) * 256 + t;
        int by = j >> 1;
        int c0 = by * PCH;
        float acc[KK];
#pragma unroll
        for (int k = 0; k < KK; k++) acc[k] = 0.f;
        {
            const float4* srcv = (const float4*)(assign + (size_t)c0 * KK);
            float4* dstv = (float4*)sa;
            for (int i = t; i < PCH * KK / 4; i += 256) dstv[i] = srcv[i];
        }
        __syncthreads();
        for (int jj = 0; jj < PCH; jj++) {
            float ev = emb[(size_t)(c0 + jj) * DD + d];
#pragma unroll
            for (int k4 = 0; k4 < 4; k4++) {
                float4 s4 = *(const float4*)&sa[jj * KK + k4 * 4];
                acc[k4 * 4 + 0] += s4.x * ev;
                acc[k4 * 4 + 1] += s4.y * ev;
                acc[k4 * 4 + 2] += s4.z * ev;
                acc[k4 * 4 + 3] += s4.w * ev;
            }
        }
        float* dst = part + (size_t)by * (KK * DD);
#pragma unroll
        for (int k = 0; k < KK; k++) dst[k * DD + d] = acc[k];
    }
}

// ---------------- finalize: reduce pooled partials + normalize + scalar losses ----------------
__global__ void finalize(const float* __restrict__ part, const float* __restrict__ scal,
                         float* __restrict__ out) {
    int bx = blockIdx.x, t = threadIdx.x;
    if (bx < 32) {
        int i = bx * 256 + t;  // 0..8191
        float s0 = 0.f, s1 = 0.f, s2 = 0.f, s3 = 0.f;
        for (int p = 0; p < 400; p += 4) {
            s0 += part[(size_t)p * 8192 + i];
            s1 += part[(size_t)(p + 1) * 8192 + i];
            s2 += part[(size_t)(p + 2) * 8192 + i];
            s3 += part[(size_t)(p + 3) * 8192 + i];
        }
        int k = i >> 9;  // i / DD
        out[800000 + i] = (s0 + s1 + s2 + s3) / (scal[k] + 1e-8f);
    } else if (t == 0) {
        float cs2 = 0.f, ds2 = 0.f;
        for (int k = 0; k < KK; k++) {
            cs2 += scal[k] * scal[k];
            ds2 += scal[16 + k] * scal[16 + k];
        }
        float two_m = (float)EE;  // sum(degrees) == E, 2m == E
        float normalizer = ds2 / two_m;
        float trace = scal[32];
        float spectral = -(trace - (float)KK * normalizer) / two_m;
        float collapse = sqrtf(cs2) / (float)NN * 4.0f - 1.0f;  // sqrt(K)=4
        float entl = 0.1f * scal[33] / (float)NN;
        out[808192] = spectral;
        out[808193] = collapse;  // COLLAPSE_REG = 1.0
        out[808194] = spectral + collapse + entl;
        out[808195] = entl;
    }
}

extern "C" void kernel_launch(void* const* d_in, const int* in_sizes, int n_in,
                              void* d_out, int out_size, void* d_ws, size_t ws_size,
                              hipStream_t stream) {
    const float* emb = (const float*)d_in[0];
    const int* esrc  = (const int*)d_in[1];
    const int* edst  = (const int*)d_in[2];
    const float* W1  = (const float*)d_in[3];
    const float* b1  = (const float*)d_in[4];
    const float* W2  = (const float*)d_in[5];
    const float* b2  = (const float*)d_in[6];
    const float* Wa  = (const float*)d_in[7];
    const float* ba  = (const float*)d_in[8];
    float* out = (float*)d_out;

    // workspace layout (4B units unless noted) — total ~56 MB
    int* indeg      = (int*)d_ws;            // 50000
    int* outdeg     = indeg + 50000;         // 50000
    int* cur        = outdeg + 50000;        // 50000
    float* pool_acc = (float*)(cur + 50000); // 8192 (unused, kept for layout)
    float* scal     = pool_acc + 8192;       // 64
    int* part       = (int*)(scal + 64);     // 256 (scan partials)
    int* off        = part + 256;            // 50001 (+pad to 50004)
    int* nbr        = off + 50004;           // 800000
    float* dis      = (float*)(nbr + 800000);// 50000
    float* degf     = dis + 50000;           // 50000
    __half* Wt1     = (__half*)(degf + 50000);   // 256*512 f16
    __half* Wt2     = Wt1 + 256 * 512;           // 256*256 f16
    __half* WaT     = Wt2 + 256 * 256;           // 16*256 f16 (unused now, layout kept)
    __half* T       = WaT + 16 * 256;            // 50000*256 f16 (25.6 MB)
    __half* Hb      = T + (size_t)NN * HH;       // 50000*256 f16 (25.6 MB)
    float* pool_part = (float*)Hb;  // 400*8192 f32 = 13.1 MB, Hb dead after agg2_assign

    // zero the atomically-accumulated region: indeg/outdeg/cur/pool_acc/scal
    hipMemsetAsync(d_ws, 0, 158256 * sizeof(int), stream);
    // degree count fused with weight transpose (count blocks first)
    count_transpose<<<dim3(1550), 256, 0, stream>>>((const int4*)esrc, (const int4*)edst,
                                                    indeg, outdeg, W1, Wt1, W2, Wt2);

    // CSR offsets: 3-phase scan (+ dis/degf in p1) — only ~1MB traffic, keeps Wt hot
    scan_p1<<<dim3(NB_SCAN), 256, 0, stream>>>(indeg, part, NN, outdeg, dis, degf);
    scan_p2<<<dim3(1), 256, 0, stream>>>(part, NB_SCAN, off + NN);
    scan_p3<<<dim3(NB_SCAN), 256, 0, stream>>>(indeg, part, off, NN);

    // conv1 GEMM fused with CSR scatter (independent; scatter hides in gemm's idle slots)
    gemm1_scatter<<<dim3(1566), 256, 0, stream>>>(emb, Wt1, T, NN,
                                                  (const int4*)esrc, (const int4*)edst,
                                                  off, cur, nbr);
    agg_selu<<<dim3(6250), 256, 0, stream>>>(T, dis, off, nbr, b1, Hb);

    // conv2 GEMM: T = Hb @ W2
    mfma_gemm<__half, HH><<<dim3(392, 2), 256, 0, stream>>>(Hb, Wt2, T, NN);
    // conv2 aggregation + skip + FUSED assignment head -> out[0..800000) + scal partials
    agg_selu_assign<<<dim3(6250), 256, 0, stream>>>(T, dis, off, nbr, b2, Hb,
                                                    Wa, ba, degf, out, scal);

    // fused tail: trace (782 blocks, f32 assignments) overlapped with pooled partials
    trace_pooled<<<dim3(1582), 256, 0, stream>>>((const int4*)esrc, (const int4*)edst,
                                                 scal, emb, out, pool_part);
    finalize<<<dim3(33), 256, 0, stream>>>(pool_part, scal, out);
}